// Round 1
// 564.371 us; speedup vs baseline: 1.0114x; 1.0114x over previous
//
#include <hip/hip_runtime.h>
#include <hip/hip_bf16.h>
#include <math.h>

// Problem constants
#define B_ 2
#define S_ 2048
#define D_ 2048
#define H_ 16
#define HD_ 128
#define TOPK_ 256
#define HIDDEN_ 8192
#define EPS_ 1e-6f

constexpr int ROWS_SEL = B_ * TOPK_;      // 512 selected rows (both batches)
constexpr int ROWS_ALL = ROWS_SEL + B_;   // +2 "unselected representative" rows

typedef __attribute__((ext_vector_type(8))) short bf16x8;
typedef __attribute__((ext_vector_type(4))) float f32x4;

__device__ __forceinline__ short f2bf(float f) {
    __hip_bfloat16 h = __float2bfloat16(f);
    return *reinterpret_cast<short*>(&h);
}

__device__ __forceinline__ float bf2f(short s) {
    union { unsigned u; float f; } c;
    c.u = ((unsigned)(unsigned short)s) << 16;
    return c.f;
}

__device__ __forceinline__ void gll16(const void* g, void* l) {
    __builtin_amdgcn_global_load_lds(
        (const __attribute__((address_space(1))) unsigned int*)g,
        (__attribute__((address_space(3))) unsigned int*)l, 16, 0, 0);
}

// ---------------------------------------------------------------------------
// Block reduction helpers
// ---------------------------------------------------------------------------
__device__ __forceinline__ float block_sum_256(float v, float* red4) {
    for (int o = 32; o; o >>= 1) v += __shfl_down(v, o);
    if ((threadIdx.x & 63) == 0) red4[threadIdx.x >> 6] = v;
    __syncthreads();
    float t = red4[0] + red4[1] + red4[2] + red4[3];
    __syncthreads();
    return t;
}

__device__ __forceinline__ float block_max_256(float v, float* red4) {
    for (int o = 32; o; o >>= 1) v = fmaxf(v, __shfl_down(v, o));
    if ((threadIdx.x & 63) == 0) red4[threadIdx.x >> 6] = v;
    __syncthreads();
    float t = fmaxf(fmaxf(red4[0], red4[1]), fmaxf(red4[2], red4[3]));
    __syncthreads();
    return t;
}

// ---------------------------------------------------------------------------
// 1. Router (exact f32), float4-vectorized
// ---------------------------------------------------------------------------
__global__ __launch_bounds__(256) void router_kernel(const float* __restrict__ x,
                                                     const float* __restrict__ rw,
                                                     float* __restrict__ tw) {
    int token = blockIdx.x;
    const float4* xr = (const float4*)(x + (long)token * D_);
    const float4* r4 = (const float4*)rw;
    float s = 0.f;
    for (int c = threadIdx.x; c < D_ / 4; c += 256) {
        float4 a = xr[c], b = r4[c];
        s += a.x * b.x + a.y * b.y + a.z * b.z + a.w * b.w;
    }
    __shared__ float red4[4];
    float tot = block_sum_256(s, red4);
    if (threadIdx.x == 0) tw[token] = tot;
}

// ---------------------------------------------------------------------------
// 2. Top-k per batch (bitonic, value desc / index asc)
// ---------------------------------------------------------------------------
__global__ __launch_bounds__(1024) void topk_kernel(const float* __restrict__ tw,
                                                    float* __restrict__ idx_out,
                                                    int* __restrict__ sel_idx,
                                                    int* __restrict__ sel_pos) {
    int b = blockIdx.x;
    __shared__ float v[S_];
    __shared__ int id[S_];
    int t = threadIdx.x;
    for (int i = t; i < S_; i += 1024) {
        v[i] = tw[b * S_ + i];
        id[i] = i;
        sel_pos[b * S_ + i] = -1;
    }
    __syncthreads();
    for (int k = 2; k <= S_; k <<= 1) {
        for (int j = k >> 1; j > 0; j >>= 1) {
            for (int i = t; i < S_; i += 1024) {
                int ixj = i ^ j;
                if (ixj > i) {
                    float va = v[i], vb = v[ixj];
                    int ia = id[i], ib = id[ixj];
                    bool before = (va > vb) || (va == vb && ia < ib);
                    bool dir = ((i & k) == 0);
                    if (dir != before) {
                        v[i] = vb; v[ixj] = va;
                        id[i] = ib; id[ixj] = ia;
                    }
                }
            }
            __syncthreads();
        }
    }
    if (t < TOPK_) {
        idx_out[b * TOPK_ + t] = (float)id[t];
        sel_idx[b * TOPK_ + t] = id[t];
        sel_pos[b * S_ + id[t]] = t;
    }
}

// ---------------------------------------------------------------------------
// 3. Gather + RMSNorm -> bf16
// ---------------------------------------------------------------------------
__global__ __launch_bounds__(256) void gather_rmsnorm_kernel(const float* __restrict__ x,
                                                             const int* __restrict__ sel_idx,
                                                             const float* __restrict__ nw,
                                                             short* __restrict__ XN) {
    int r = blockIdx.x;
    int b = r >> 8;
    int s = sel_idx[r];
    const float* xr = x + ((long)b * S_ + s) * D_;
    __shared__ float buf[D_];
    __shared__ float red4[4];
    float ss = 0.f;
    for (int c = threadIdx.x; c < D_; c += 256) {
        float vv = xr[c];
        buf[c] = vv;
        ss += vv * vv;
    }
    float tot = block_sum_256(ss, red4);
    float scale = rsqrtf(tot / D_ + EPS_);
    for (int c = threadIdx.x; c < D_; c += 256)
        XN[(long)r * D_ + c] = f2bf(buf[c] * scale * nw[c]);
}

// ---------------------------------------------------------------------------
// MFMA GEMM with f32 weights consumed directly (no global pre-transpose).
// C(f32 partial) = A(bf16 MxKtot) @ B(f32 Ktot x N, row-major), split-K.
// grid.z = zmat*splits + sp. Partial -> Cb + zmat*czStride + sp*spStride.
//
// A staged bf16 via global_load_lds.
// B staged global->reg (16 coalesced dword loads/thread, lane-consecutive
// columns) -> cvt to bf16 once -> TRANSPOSED LDS tile Bs[n][k] with
// chunk-XOR swizzle (chunk ^= (n>>1)&3, row stride 64B):
//   - staging ds_write_b128: 8 lanes per 16B slot over 8 slots -> conflict-free
//   - fragment ds_read_b128: uniform 8 lanes/slot -> conflict-free
// This replaces the old per-fragment path (32 conflicted ds_read_b32 +
// 32 f2bf per thread per k-step) that left MfmaUtil at 15%.
// ---------------------------------------------------------------------------
__global__ __launch_bounds__(256) void gemm_mfma_w(
    const short* __restrict__ A,
    const float* __restrict__ B0, const float* __restrict__ B1, const float* __restrict__ B2,
    float* __restrict__ Cb, long czStride, long spStride,
    int M, int N, int Ktot, int K_per, int splits) {
    __shared__ short As[128 * 32];   // 8 KB  [row][k] bf16
    __shared__ short Bs[128 * 32];   // 8 KB  [n][chunk^swz][8] bf16 (transposed)
    int z = blockIdx.z;
    int zmat = z / splits, sp = z % splits;
    const float* Bm = (zmat == 0) ? B0 : (zmat == 1) ? B1 : B2;
    float* C = Cb + (long)zmat * czStride + (long)sp * spStride;
    int kbase = sp * K_per;
    int row0 = blockIdx.y * 128, col0 = blockIdx.x * 128;
    int t = threadIdx.x;
    int lane = t & 63, w = t >> 6;
    int l16 = lane & 15, quad = lane >> 4;
    int wr = (w >> 1) * 64, wc = (w & 1) * 64;
    int arr = t >> 2, ach = (t & 3) * 8;     // A staging: row arr(+64), k-chunk ach
    int bn = t & 127, bkh = (t >> 7) * 16;   // B staging: column bn, k-half bkh
    int bswz = (bn >> 1) & 3;
    short* bw0 = Bs + bn * 32 + ((((bkh >> 3) + 0) ^ bswz) << 3);
    short* bw1 = Bs + bn * 32 + ((((bkh >> 3) + 1) ^ bswz) << 3);
    const float* bcol = Bm + col0 + bn;
    f32x4 acc[4][4] = {};
    for (int k0 = kbase; k0 < kbase + K_per; k0 += 32) {
        __syncthreads();
        #pragma unroll
        for (int rd = 0; rd < 2; ++rd) {
            int ar = row0 + arr + rd * 64; ar = (ar < M) ? ar : (M - 1);
            gll16(A + (size_t)ar * Ktot + k0 + ach, (char*)As + rd * 4096 + t * 16);
        }
        // B: 16 rows of one f32 column -> regs -> bf16 -> swizzled transposed LDS
        const float* src = bcol + (size_t)(k0 + bkh) * N;
        float f[16];
        #pragma unroll
        for (int r = 0; r < 16; ++r) f[r] = src[(size_t)r * N];
        union { short s[8]; bf16x8 v; } u0, u1;
        #pragma unroll
        for (int r = 0; r < 8; ++r) u0.s[r] = f2bf(f[r]);
        #pragma unroll
        for (int r = 0; r < 8; ++r) u1.s[r] = f2bf(f[r + 8]);
        *(bf16x8*)bw0 = u0.v;
        *(bf16x8*)bw1 = u1.v;
        __syncthreads();
        bf16x8 af[4], bfr[4];
        #pragma unroll
        for (int i = 0; i < 4; ++i)
            af[i] = *(const bf16x8*)(As + (wr + i * 16 + l16) * 32 + quad * 8);
        #pragma unroll
        for (int j = 0; j < 4; ++j) {
            int n = wc + j * 16 + l16;
            bfr[j] = *(const bf16x8*)(Bs + n * 32 + ((quad ^ ((n >> 1) & 3)) << 3));
        }
        #pragma unroll
        for (int i = 0; i < 4; ++i)
            #pragma unroll
            for (int j = 0; j < 4; ++j)
                acc[i][j] = __builtin_amdgcn_mfma_f32_16x16x32_bf16(af[i], bfr[j], acc[i][j], 0, 0, 0);
    }
    #pragma unroll
    for (int i = 0; i < 4; ++i) {
        #pragma unroll
        for (int r = 0; r < 4; ++r) {
            int row = row0 + wr + i * 16 + quad * 4 + r;
            if (row < M) {
                #pragma unroll
                for (int j = 0; j < 4; ++j)
                    C[(size_t)row * N + col0 + wc + j * 16 + l16] = acc[i][j][r];
            }
        }
    }
}

// ---------------------------------------------------------------------------
// Batched bf16 MFMA GEMM for attention: C = A @ B^T per z.
// A: rows M, k-contig, row stride lda; B: rows N, k-contig, row stride ldb.
// Per-z offsets: (z/inner)*sXo + (z%inner)*sXi. OBF: write bf16 else f32.
// ---------------------------------------------------------------------------
template <bool OBF>
__global__ __launch_bounds__(256) void gemm_mfma_attn(
    const short* __restrict__ A, long sAo, long sAi, int lda,
    const short* __restrict__ Bm, long sBo, long sBi, int ldb,
    void* __restrict__ Cv, long sCo, long sCi, int ldc,
    int M, int N, int K, int inner) {
    __shared__ short smem[2 * 128 * 32];
    short* As = smem;
    short* Bs = smem + 128 * 32;
    int z = blockIdx.z;
    int zo = z / inner, zi = z % inner;
    const short* Ab = A + (long)zo * sAo + (long)zi * sAi;
    const short* Bb = Bm + (long)zo * sBo + (long)zi * sBi;
    long cbase = (long)zo * sCo + (long)zi * sCi;
    int row0 = blockIdx.y * 128, col0 = blockIdx.x * 128;
    int t = threadIdx.x;
    int lane = t & 63, w = t >> 6;
    int l16 = lane & 15, quad = lane >> 4;
    int wr = (w >> 1) * 64, wc = (w & 1) * 64;
    int rr = t >> 2, ch = (t & 3) * 8;
    f32x4 acc[4][4] = {};
    for (int k0 = 0; k0 < K; k0 += 32) {
        __syncthreads();
        #pragma unroll
        for (int rd = 0; rd < 2; ++rd) {
            int r = rr + rd * 64;
            int ar = row0 + r; ar = (ar < M) ? ar : (M - 1);
            gll16(Ab + (size_t)ar * lda + k0 + ch, (char*)As + rd * 4096 + t * 16);
            gll16(Bb + (size_t)(col0 + r) * ldb + k0 + ch, (char*)Bs + rd * 4096 + t * 16);
        }
        __syncthreads();
        bf16x8 af[4], bfr[4];
        #pragma unroll
        for (int i = 0; i < 4; ++i)
            af[i] = *(const bf16x8*)(As + (wr + i * 16 + l16) * 32 + quad * 8);
        #pragma unroll
        for (int j = 0; j < 4; ++j)
            bfr[j] = *(const bf16x8*)(Bs + (wc + j * 16 + l16) * 32 + quad * 8);
        #pragma unroll
        for (int i = 0; i < 4; ++i)
            #pragma unroll
            for (int j = 0; j < 4; ++j)
                acc[i][j] = __builtin_amdgcn_mfma_f32_16x16x32_bf16(af[i], bfr[j], acc[i][j], 0, 0, 0);
    }
    #pragma unroll
    for (int i = 0; i < 4; ++i) {
        #pragma unroll
        for (int r = 0; r < 4; ++r) {
            int row = row0 + wr + i * 16 + quad * 4 + r;
            if (row < M) {
                #pragma unroll
                for (int j = 0; j < 4; ++j) {
                    long idx = cbase + (size_t)row * ldc + col0 + wc + j * 16 + l16;
                    if (OBF) ((short*)Cv)[idx] = f2bf(acc[i][j][r]);
                    else     ((float*)Cv)[idx] = acc[i][j][r];
                }
            }
        }
    }
}

// ---------------------------------------------------------------------------
// QKV finish: reduce split-K partials + rotary -> bf16 Qbf (pre-scaled), Kbf, Vbf
// Cp layout: [sp][mat(q,k,v)][512][2048]
// ---------------------------------------------------------------------------
__global__ __launch_bounds__(256) void qkv_finish(
    const float* __restrict__ Cp, const float* __restrict__ fc,
    const int* __restrict__ sel_idx, const int* __restrict__ sp0,
    short* __restrict__ Qbf, short* __restrict__ Kbf, short* __restrict__ Vbf,
    int splits) {
    int r = blockIdx.x;
    int s = sel_idx[r];
    int pos = sp0[0] + s;
    const float* f = fc + (long)pos * HD_;
    const long matS = (long)ROWS_SEL * D_;
    const long spS = 3 * matS;
    const float* qp = Cp + (long)r * D_;
    const float* kp = qp + matS;
    const float* vp = qp + 2 * matS;
    const float qscale = 0.08838834764831845f;  // 1/sqrt(128)
    for (int p = threadIdx.x; p < (D_ / 2); p += 256) {
        int h = p >> 6, d2 = p & 63;
        int e0 = h * HD_ + d2 * 2;
        float q0 = 0.f, q1 = 0.f, k0 = 0.f, k1 = 0.f, v0 = 0.f, v1 = 0.f;
        for (int sp = 0; sp < splits; ++sp) {
            long off = (long)sp * spS;
            q0 += qp[off + e0]; q1 += qp[off + e0 + 1];
            k0 += kp[off + e0]; k1 += kp[off + e0 + 1];
            v0 += vp[off + e0]; v1 += vp[off + e0 + 1];
        }
        float c = f[d2 * 2], sn = f[d2 * 2 + 1];
        Qbf[(long)r * D_ + e0]     = f2bf((q0 * c - q1 * sn) * qscale);
        Qbf[(long)r * D_ + e0 + 1] = f2bf((q0 * sn + q1 * c) * qscale);
        Kbf[(long)r * D_ + e0]     = f2bf(k0 * c - k1 * sn);
        Kbf[(long)r * D_ + e0 + 1] = f2bf(k0 * sn + k1 * c);
        Vbf[(long)r * D_ + e0]     = f2bf(v0);
        Vbf[(long)r * D_ + e0 + 1] = f2bf(v1);
    }
}

// ---------------------------------------------------------------------------
// V transpose per (b,h): Vbf[b*256+key][h*128+d] -> VT[z][d][key] (bf16)
// grid: (keytiles=4, dimtiles=2, z=32)
// ---------------------------------------------------------------------------
__global__ __launch_bounds__(256) void vt_kernel(const short* __restrict__ Vbf,
                                                 short* __restrict__ VT) {
    int z = blockIdx.z;
    int b = z >> 4, h = z & 15;
    int key0 = blockIdx.x * 64, d0 = blockIdx.y * 64;
    __shared__ short L[64][72];
    int t = threadIdx.x;
    int kr = t >> 3, dc = (t & 7) * 8;
    #pragma unroll
    for (int rr = 0; rr < 2; ++rr) {
        int key = kr + rr * 32;
        union { short s[8]; int4 v; } u;
        u.v = *(const int4*)&Vbf[(size_t)(b * 256 + key0 + key) * D_ + h * 128 + d0 + dc];
        #pragma unroll
        for (int j = 0; j < 8; ++j) L[key][dc + j] = u.s[j];
    }
    __syncthreads();
    int dr = t >> 3, kc = (t & 7) * 8;
    #pragma unroll
    for (int rr = 0; rr < 2; ++rr) {
        int d = dr + rr * 32;
        union { short s[8]; int4 v; } u;
        #pragma unroll
        for (int j = 0; j < 8; ++j) u.s[j] = L[kc + j][d];
        *(int4*)&VT[((size_t)z * 128 + d0 + d) * 256 + key0 + kc] = u.v;
    }
}

// ---------------------------------------------------------------------------
// Softmax over each 256-score row -> bf16 probs
// ---------------------------------------------------------------------------
__global__ __launch_bounds__(256) void softmax_kernel(const float* __restrict__ SC,
                                                      short* __restrict__ Pbf) {
    long row = blockIdx.x;
    const float* p = SC + row * 256;
    int t = threadIdx.x;
    float v = p[t];
    __shared__ float red4[4];
    float m = block_max_256(v, red4);
    float e = expf(v - m);
    float s = block_sum_256(e, red4);
    Pbf[row * 256 + t] = f2bf(e / s);
}

// ---------------------------------------------------------------------------
// vbar: mean of selected V rows per batch -> Obf rows 512+b (bf16)
// ---------------------------------------------------------------------------
__global__ __launch_bounds__(256) void vbar_kernel(const short* __restrict__ Vbf,
                                                   short* __restrict__ Obf) {
    int b = blockIdx.y;
    int c = blockIdx.x * 256 + threadIdx.x;
    float s = 0.f;
    for (int i = 0; i < TOPK_; ++i) s += bf2f(Vbf[((long)b * TOPK_ + i) * D_ + c]);
    Obf[(long)(ROWS_SEL + b) * D_ + c] = f2bf(s * (1.f / TOPK_));
}

// ---------------------------------------------------------------------------
// Residual + RMSNorm, fused wo split-K reduce. Pp: [sp][514][2048]
// ---------------------------------------------------------------------------
__global__ __launch_bounds__(256) void resid_rmsnorm_kernel(const float* __restrict__ Pp,
                                                            int splits,
                                                            const float* __restrict__ x,
                                                            const int* __restrict__ sel_idx,
                                                            const float* __restrict__ nw,
                                                            short* __restrict__ HN) {
    int r = blockIdx.x;
    __shared__ float buf[D_];
    __shared__ float red4[4];
    const long spS = (long)ROWS_ALL * D_;
    const float* pr = Pp + (long)r * D_;
    const float* xr = nullptr;
    if (r < ROWS_SEL) {
        int b = r >> 8;
        int s = sel_idx[r];
        xr = x + ((long)b * S_ + s) * D_;
    }
    float ss = 0.f;
    for (int c = threadIdx.x; c < D_; c += 256) {
        float v = xr ? xr[c] : 0.f;
        for (int sp = 0; sp < splits; ++sp) v += pr[(long)sp * spS + c];
        buf[c] = v;
        ss += v * v;
    }
    float tot = block_sum_256(ss, red4);
    float scale = rsqrtf(tot / D_ + EPS_);
    for (int c = threadIdx.x; c < D_; c += 256)
        HN[(long)r * D_ + c] = f2bf(buf[c] * scale * nw[c]);
}

// ---------------------------------------------------------------------------
// reduce w1/w3 partials + silu-mul -> bf16. Gp: [mat][sp][514][8192], splits=2
// ---------------------------------------------------------------------------
__global__ __launch_bounds__(256) void reduce_silu_kernel(const float* __restrict__ Gp,
                                                          short* __restrict__ FF, long n) {
    long i = (long)blockIdx.x * 256 + threadIdx.x;
    if (i < n) {
        const long cz = (long)ROWS_ALL * HIDDEN_;
        float a = Gp[i] + Gp[cz + i];
        float g = Gp[2 * cz + i] + Gp[3 * cz + i];
        FF[i] = f2bf((a / (1.f + expf(-a))) * g);
    }
}

// ---------------------------------------------------------------------------
// reduce w2 partials (8) -> OUTR, float4 vectorized
// ---------------------------------------------------------------------------
__global__ __launch_bounds__(256) void w2_reduce_kernel(const float* __restrict__ Wp,
                                                        float* __restrict__ OUTR, long n4) {
    long i = (long)blockIdx.x * 256 + threadIdx.x;
    if (i < n4) {
        const long spS4 = (long)ROWS_ALL * D_ / 4;
        float4 s = ((const float4*)Wp)[i];
        for (int sp = 1; sp < 8; ++sp) {
            float4 v = ((const float4*)Wp)[(long)sp * spS4 + i];
            s.x += v.x; s.y += v.y; s.z += v.z; s.w += v.w;
        }
        ((float4*)OUTR)[i] = s;
    }
}

// ---------------------------------------------------------------------------
// Scatter rows to output (float4)
// ---------------------------------------------------------------------------
__global__ __launch_bounds__(256) void scatter_kernel(const float* __restrict__ OUTR,
                                                      const int* __restrict__ sel_pos,
                                                      float* __restrict__ out) {
    int blk = blockIdx.x;
    int b = blk >> 11;
    int p = sel_pos[blk];
    int row = (p >= 0) ? (b * TOPK_ + p) : (ROWS_SEL + b);
    const float4* src = (const float4*)(OUTR + (long)row * D_);
    float4* dst = (float4*)(out + (long)blk * D_);
    for (int c = threadIdx.x; c < D_ / 4; c += 256) dst[c] = src[c];
}

// ---------------------------------------------------------------------------
extern "C" void kernel_launch(void* const* d_in, const int* in_sizes, int n_in,
                              void* d_out, int out_size, void* d_ws, size_t ws_size,
                              hipStream_t stream) {
    const float* x        = (const float*)d_in[0];
    const int*   startpos = (const int*)d_in[1];
    const float* freqs    = (const float*)d_in[2];
    const float* router_w = (const float*)d_in[3];
    const float* wq       = (const float*)d_in[4];
    const float* wk       = (const float*)d_in[5];
    const float* wv       = (const float*)d_in[6];
    const float* wo       = (const float*)d_in[7];
    const float* w1       = (const float*)d_in[8];
    const float* w2       = (const float*)d_in[9];
    const float* w3       = (const float*)d_in[10];
    const float* attn_w   = (const float*)d_in[11];
    const float* ffn_w    = (const float*)d_in[12];

    float* out     = (float*)d_out;
    float* tw_out  = out + (long)B_ * S_ * D_;
    float* idx_out = tw_out + (long)B_ * S_;

    char* ws = (char*)d_ws;
    auto alloc = [&](size_t bytes) -> void* {
        void* p = (void*)ws;
        ws += (bytes + 255) / 256 * 256;
        return p;
    };
    int*   sel_idx = (int*)alloc((size_t)B_ * TOPK_ * sizeof(int));
    int*   sel_pos = (int*)alloc((size_t)B_ * S_ * sizeof(int));
    short* XNbf = (short*)alloc((size_t)ROWS_SEL * D_ * sizeof(short));
    short* Qbf  = (short*)alloc((size_t)ROWS_SEL * D_ * sizeof(short));
    short* Kbf  = (short*)alloc((size_t)ROWS_SEL * D_ * sizeof(short));
    short* Vbf  = (short*)alloc((size_t)ROWS_SEL * D_ * sizeof(short));
    short* VT   = (short*)alloc((size_t)B_ * H_ * HD_ * TOPK_ * sizeof(short));
    float* SC   = (float*)alloc((size_t)B_ * H_ * TOPK_ * TOPK_ * sizeof(float));
    short* Pbf  = (short*)alloc((size_t)B_ * H_ * TOPK_ * TOPK_ * sizeof(short));
    short* Obf  = (short*)alloc((size_t)ROWS_ALL * D_ * sizeof(short));
    short* HNbf = (short*)alloc((size_t)ROWS_ALL * D_ * sizeof(short));
    short* FFbf = (short*)alloc((size_t)ROWS_ALL * HIDDEN_ * sizeof(short));
    float* OUTR = (float*)alloc((size_t)ROWS_ALL * D_ * sizeof(float));
    // Split-K partial arena: max = w1/w3 partials 4 * 514 * 8192 f32 = 67.4 MB
    float* Gar  = (float*)alloc((size_t)4 * ROWS_ALL * HIDDEN_ * sizeof(float));

    // 1. Router
    router_kernel<<<B_ * S_, 256, 0, stream>>>(x, router_w, tw_out);
    // 2. Top-k
    topk_kernel<<<B_, 1024, 0, stream>>>(tw_out, idx_out, sel_idx, sel_pos);
    // 3. Gather + RMSNorm -> bf16
    gather_rmsnorm_kernel<<<ROWS_SEL, 256, 0, stream>>>(x, sel_idx, attn_w, XNbf);
    // 4. QKV GEMM (f32 weights direct), split-K=4: partials [sp][mat][512][2048]
    {
        dim3 g(D_ / 128, ROWS_SEL / 128, 3 * 4);
        gemm_mfma_w<<<g, 256, 0, stream>>>(XNbf, wq, wk, wv,
                                           Gar, (long)ROWS_SEL * D_, (long)3 * ROWS_SEL * D_,
                                           ROWS_SEL, D_, D_, D_ / 4, 4);
    }
    // 5. Reduce + rotary -> bf16 Q (pre-scaled), K, V
    qkv_finish<<<ROWS_SEL, 256, 0, stream>>>(Gar, freqs, sel_idx, startpos, Qbf, Kbf, Vbf, 4);
    // 6. V transpose per (b,h)
    {
        dim3 g(4, 2, B_ * H_);
        vt_kernel<<<g, 256, 0, stream>>>(Vbf, VT);
    }
    // 7. Scores = (Q/sqrt(HD)) K^T  (bf16 MFMA, f32 out)
    {
        dim3 g(2, 2, B_ * H_);
        gemm_mfma_attn<false><<<g, 256, 0, stream>>>(
            Qbf, (long)TOPK_ * D_, HD_, D_,
            Kbf, (long)TOPK_ * D_, HD_, D_,
            SC, (long)H_ * TOPK_ * TOPK_, (long)TOPK_ * TOPK_, TOPK_,
            TOPK_, TOPK_, HD_, H_);
    }
    // 8. Softmax -> bf16 probs
    softmax_kernel<<<B_ * H_ * TOPK_, 256, 0, stream>>>(SC, Pbf);
    // 9. O = P @ V (bf16 MFMA via VT), bf16 out into Obf (head-strided)
    {
        dim3 g(1, 2, B_ * H_);
        gemm_mfma_attn<true><<<g, 256, 0, stream>>>(
            Pbf, (long)H_ * TOPK_ * TOPK_, (long)TOPK_ * TOPK_, TOPK_,
            VT, (long)H_ * HD_ * TOPK_, (long)HD_ * TOPK_, TOPK_,
            Obf, (long)TOPK_ * D_, HD_, D_,
            TOPK_, HD_, TOPK_, H_);
    }
    // 10. vbar rows -> bf16
    {
        dim3 g(D_ / 256, B_, 1);
        vbar_kernel<<<g, 256, 0, stream>>>(Vbf, Obf);
    }
    // 11. wo projection, split-K=8: partials [sp][514][2048]
    {
        dim3 g(D_ / 128, (ROWS_ALL + 127) / 128, 8);
        gemm_mfma_w<<<g, 256, 0, stream>>>(Obf, wo, wo, wo,
                                           Gar, 0, (long)ROWS_ALL * D_,
                                           ROWS_ALL, D_, D_, D_ / 8, 8);
    }
    // 12. Residual + RMSNorm (fused wo-reduce) -> bf16
    resid_rmsnorm_kernel<<<ROWS_ALL, 256, 0, stream>>>(Gar, 8, x, sel_idx, ffn_w, HNbf);
    // 13. w1/w3 up-projections, split-K=2: partials [mat][sp][514][8192]
    {
        dim3 g(HIDDEN_ / 128, (ROWS_ALL + 127) / 128, 2 * 2);
        gemm_mfma_w<<<g, 256, 0, stream>>>(HNbf, w1, w3, w3,
                                           Gar, (long)2 * ROWS_ALL * HIDDEN_, (long)ROWS_ALL * HIDDEN_,
                                           ROWS_ALL, HIDDEN_, D_, D_ / 2, 2);
    }
    // 14. reduce + silu-mul -> bf16
    {
        long n = (long)ROWS_ALL * HIDDEN_;
        reduce_silu_kernel<<<(unsigned)((n + 255) / 256), 256, 0, stream>>>(Gar, FFbf, n);
    }
    // 15. w2 down-projection, split-K=8: partials [sp][514][2048]
    {
        dim3 g(D_ / 128, (ROWS_ALL + 127) / 128, 8);
        gemm_mfma_w<<<g, 256, 0, stream>>>(FFbf, w2, w2, w2,
                                           Gar, 0, (long)ROWS_ALL * D_,
                                           ROWS_ALL, D_, HIDDEN_, HIDDEN_ / 8, 8);
    }
    // 16. reduce w2 partials
    {
        long n4 = (long)ROWS_ALL * D_ / 4;
        w2_reduce_kernel<<<(unsigned)((n4 + 255) / 256), 256, 0, stream>>>(Gar, OUTR, n4);
    }
    // 17. Scatter
    scatter_kernel<<<B_ * S_, 256, 0, stream>>>(OUTR, sel_pos, out);
}

// Round 2
// 558.969 us; speedup vs baseline: 1.0212x; 1.0097x over previous
//
#include <hip/hip_runtime.h>
#include <hip/hip_bf16.h>
#include <math.h>

// Problem constants
#define B_ 2
#define S_ 2048
#define D_ 2048
#define H_ 16
#define HD_ 128
#define TOPK_ 256
#define HIDDEN_ 8192
#define EPS_ 1e-6f

constexpr int ROWS_SEL = B_ * TOPK_;      // 512 selected rows (both batches)
constexpr int ROWS_ALL = ROWS_SEL + B_;   // +2 "unselected representative" rows

typedef __attribute__((ext_vector_type(8))) short bf16x8;
typedef __attribute__((ext_vector_type(4))) float f32x4;

__device__ __forceinline__ short f2bf(float f) {
    __hip_bfloat16 h = __float2bfloat16(f);
    return *reinterpret_cast<short*>(&h);
}

__device__ __forceinline__ float bf2f(short s) {
    union { unsigned u; float f; } c;
    c.u = ((unsigned)(unsigned short)s) << 16;
    return c.f;
}

__device__ __forceinline__ void gll16(const void* g, void* l) {
    __builtin_amdgcn_global_load_lds(
        (const __attribute__((address_space(1))) unsigned int*)g,
        (__attribute__((address_space(3))) unsigned int*)l, 16, 0, 0);
}

// ---------------------------------------------------------------------------
// Block reduction helpers
// ---------------------------------------------------------------------------
__device__ __forceinline__ float block_sum_256(float v, float* red4) {
    for (int o = 32; o; o >>= 1) v += __shfl_down(v, o);
    if ((threadIdx.x & 63) == 0) red4[threadIdx.x >> 6] = v;
    __syncthreads();
    float t = red4[0] + red4[1] + red4[2] + red4[3];
    __syncthreads();
    return t;
}

__device__ __forceinline__ float block_max_256(float v, float* red4) {
    for (int o = 32; o; o >>= 1) v = fmaxf(v, __shfl_down(v, o));
    if ((threadIdx.x & 63) == 0) red4[threadIdx.x >> 6] = v;
    __syncthreads();
    float t = fmaxf(fmaxf(red4[0], red4[1]), fmaxf(red4[2], red4[3]));
    __syncthreads();
    return t;
}

// ---------------------------------------------------------------------------
// 1. Router (exact f32), float4-vectorized
// ---------------------------------------------------------------------------
__global__ __launch_bounds__(256) void router_kernel(const float* __restrict__ x,
                                                     const float* __restrict__ rw,
                                                     float* __restrict__ tw) {
    int token = blockIdx.x;
    const float4* xr = (const float4*)(x + (long)token * D_);
    const float4* r4 = (const float4*)rw;
    float s = 0.f;
    for (int c = threadIdx.x; c < D_ / 4; c += 256) {
        float4 a = xr[c], b = r4[c];
        s += a.x * b.x + a.y * b.y + a.z * b.z + a.w * b.w;
    }
    __shared__ float red4[4];
    float tot = block_sum_256(s, red4);
    if (threadIdx.x == 0) tw[token] = tot;
}

// ---------------------------------------------------------------------------
// 2. Top-k per batch (bitonic, value desc / index asc)
// ---------------------------------------------------------------------------
__global__ __launch_bounds__(1024) void topk_kernel(const float* __restrict__ tw,
                                                    float* __restrict__ idx_out,
                                                    int* __restrict__ sel_idx,
                                                    int* __restrict__ sel_pos) {
    int b = blockIdx.x;
    __shared__ float v[S_];
    __shared__ int id[S_];
    int t = threadIdx.x;
    for (int i = t; i < S_; i += 1024) {
        v[i] = tw[b * S_ + i];
        id[i] = i;
        sel_pos[b * S_ + i] = -1;
    }
    __syncthreads();
    for (int k = 2; k <= S_; k <<= 1) {
        for (int j = k >> 1; j > 0; j >>= 1) {
            for (int i = t; i < S_; i += 1024) {
                int ixj = i ^ j;
                if (ixj > i) {
                    float va = v[i], vb = v[ixj];
                    int ia = id[i], ib = id[ixj];
                    bool before = (va > vb) || (va == vb && ia < ib);
                    bool dir = ((i & k) == 0);
                    if (dir != before) {
                        v[i] = vb; v[ixj] = va;
                        id[i] = ib; id[ixj] = ia;
                    }
                }
            }
            __syncthreads();
        }
    }
    if (t < TOPK_) {
        idx_out[b * TOPK_ + t] = (float)id[t];
        sel_idx[b * TOPK_ + t] = id[t];
        sel_pos[b * S_ + id[t]] = t;
    }
}

// ---------------------------------------------------------------------------
// 3. Gather + RMSNorm -> bf16
// ---------------------------------------------------------------------------
__global__ __launch_bounds__(256) void gather_rmsnorm_kernel(const float* __restrict__ x,
                                                             const int* __restrict__ sel_idx,
                                                             const float* __restrict__ nw,
                                                             short* __restrict__ XN) {
    int r = blockIdx.x;
    int b = r >> 8;
    int s = sel_idx[r];
    const float* xr = x + ((long)b * S_ + s) * D_;
    __shared__ float buf[D_];
    __shared__ float red4[4];
    float ss = 0.f;
    for (int c = threadIdx.x; c < D_; c += 256) {
        float vv = xr[c];
        buf[c] = vv;
        ss += vv * vv;
    }
    float tot = block_sum_256(ss, red4);
    float scale = rsqrtf(tot / D_ + EPS_);
    for (int c = threadIdx.x; c < D_; c += 256)
        XN[(long)r * D_ + c] = f2bf(buf[c] * scale * nw[c]);
}

// ---------------------------------------------------------------------------
// MFMA GEMM with f32 weights consumed directly (no global pre-transpose).
// C(f32 partial) = A(bf16 MxKtot) @ B(f32 Ktot x N, row-major), split-K.
// grid.z = zmat*splits + sp. Partial -> Cb + zmat*czStride + sp*spStride.
//
// Pipelined (T3/T4 minimum-2-phase, counted vmcnt):
//   - LDS double-buffered: As[2] (gll16-staged bf16), Bs[2] (reg-staged,
//     cvt'd, transposed+chunk-XOR-swizzled bf16).
//   - Per iter: wait B-regs(k) [vmcnt(2)] -> cvt+ds_write Bs[cur] ->
//     issue B-regs(k+1) + gll16 A(k+1)->As[cur^1] -> wait A(k)
//     [vmcnt(18) lgkmcnt(0)] -> s_barrier -> frag reads + 16 MFMA ->
//     s_barrier.
//   - Outstanding-load ledger (issue order per iter: 16 B-dword, 2 gll16):
//     vmcnt(2) leaves only the A(k) gll16 pair; vmcnt(18) leaves only the
//     k+1 prefetch batch. Raw s_barrier (no vmcnt(0) drain) is what lets
//     the prefetch stay in flight across the barrier.
// ---------------------------------------------------------------------------
__global__ __launch_bounds__(256) void gemm_mfma_w(
    const short* __restrict__ A,
    const float* __restrict__ B0, const float* __restrict__ B1, const float* __restrict__ B2,
    float* __restrict__ Cb, long czStride, long spStride,
    int M, int N, int Ktot, int K_per, int splits) {
    __shared__ short As[2][128 * 32];   // 2 x 8 KB  [row][k] bf16
    __shared__ short Bs[2][128 * 32];   // 2 x 8 KB  [n][chunk^swz][8] bf16
    int z = blockIdx.z;
    int zmat = z / splits, sp = z % splits;
    const float* Bm = (zmat == 0) ? B0 : (zmat == 1) ? B1 : B2;
    float* C = Cb + (long)zmat * czStride + (long)sp * spStride;
    int kbase = sp * K_per;
    int row0 = blockIdx.y * 128, col0 = blockIdx.x * 128;
    int t = threadIdx.x;
    int lane = t & 63, w = t >> 6;
    int l16 = lane & 15, quad = lane >> 4;
    int wr = (w >> 1) * 64, wc = (w & 1) * 64;
    int arr = t >> 2, ach = (t & 3) * 8;     // A staging: row arr(+64), k-chunk ach
    int bn = t & 127, bkh = (t >> 7) * 16;   // B staging: column bn, k-half bkh
    int bswz = (bn >> 1) & 3;
    int bw0o = bn * 32 + ((((bkh >> 3) + 0) ^ bswz) << 3);
    int bw1o = bn * 32 + ((((bkh >> 3) + 1) ^ bswz) << 3);
    const float* bcol = Bm + col0 + bn;
    int ar0 = row0 + arr;      ar0 = (ar0 < M) ? ar0 : (M - 1);
    int ar1 = row0 + arr + 64; ar1 = (ar1 < M) ? ar1 : (M - 1);
    const short* Ap0 = A + (size_t)ar0 * Ktot + ach;
    const short* Ap1 = A + (size_t)ar1 * Ktot + ach;

    f32x4 acc[4][4] = {};
    float f[16];

    // Prologue: issue B-regs(k0) then A(k0)->As[0]  (order matters for vmcnt)
    {
        const float* src = bcol + (size_t)(kbase + bkh) * N;
        #pragma unroll
        for (int r = 0; r < 16; ++r) f[r] = src[(size_t)r * N];
        gll16(Ap0 + kbase, (char*)As[0] + t * 16);
        gll16(Ap1 + kbase, (char*)As[0] + 4096 + t * 16);
    }

    int nk = K_per >> 5;
    for (int kt = 0; kt < nk; ++kt) {
        int cur = kt & 1;
        short* Bsc = Bs[cur];
        // wait for this tile's 16 B dword loads (2 newer gll16 still in flight)
        asm volatile("s_waitcnt vmcnt(2)" ::: "memory");
        __builtin_amdgcn_sched_barrier(0);
        union { short s[8]; bf16x8 v; } u0, u1;
        #pragma unroll
        for (int r = 0; r < 8; ++r) u0.s[r] = f2bf(f[r]);
        #pragma unroll
        for (int r = 0; r < 8; ++r) u1.s[r] = f2bf(f[r + 8]);
        *(bf16x8*)(Bsc + bw0o) = u0.v;
        *(bf16x8*)(Bsc + bw1o) = u1.v;
        if (kt + 1 < nk) {
            // prefetch next tile: 16 B dwords, then 2 A gll16 -> other buffer
            int k1 = kbase + (kt + 1) * 32;
            const float* src = bcol + (size_t)(k1 + bkh) * N;
            #pragma unroll
            for (int r = 0; r < 16; ++r) f[r] = src[(size_t)r * N];
            char* Adst = (char*)As[cur ^ 1];
            gll16(Ap0 + k1, Adst + t * 16);
            gll16(Ap1 + k1, Adst + 4096 + t * 16);
            // wait A(k) gll16 (18 newer prefetch ops remain in flight)
            asm volatile("s_waitcnt vmcnt(18) lgkmcnt(0)" ::: "memory");
        } else {
            asm volatile("s_waitcnt vmcnt(0) lgkmcnt(0)" ::: "memory");
        }
        __builtin_amdgcn_sched_barrier(0);
        __builtin_amdgcn_s_barrier();
        __builtin_amdgcn_sched_barrier(0);
        const short* Asc = As[cur];
        bf16x8 af[4], bfr[4];
        #pragma unroll
        for (int i = 0; i < 4; ++i)
            af[i] = *(const bf16x8*)(Asc + (wr + i * 16 + l16) * 32 + quad * 8);
        #pragma unroll
        for (int j = 0; j < 4; ++j) {
            int n = wc + j * 16 + l16;
            bfr[j] = *(const bf16x8*)(Bsc + n * 32 + ((quad ^ ((n >> 1) & 3)) << 3));
        }
        #pragma unroll
        for (int i = 0; i < 4; ++i)
            #pragma unroll
            for (int j = 0; j < 4; ++j)
                acc[i][j] = __builtin_amdgcn_mfma_f32_16x16x32_bf16(af[i], bfr[j], acc[i][j], 0, 0, 0);
        __builtin_amdgcn_s_barrier();
        __builtin_amdgcn_sched_barrier(0);
    }
    #pragma unroll
    for (int i = 0; i < 4; ++i) {
        #pragma unroll
        for (int r = 0; r < 4; ++r) {
            int row = row0 + wr + i * 16 + quad * 4 + r;
            if (row < M) {
                #pragma unroll
                for (int j = 0; j < 4; ++j)
                    C[(size_t)row * N + col0 + wc + j * 16 + l16] = acc[i][j][r];
            }
        }
    }
}

// ---------------------------------------------------------------------------
// Batched bf16 MFMA GEMM for attention: C = A @ B^T per z.
// A: rows M, k-contig, row stride lda; B: rows N, k-contig, row stride ldb.
// Per-z offsets: (z/inner)*sXo + (z%inner)*sXi. OBF: write bf16 else f32.
// ---------------------------------------------------------------------------
template <bool OBF>
__global__ __launch_bounds__(256) void gemm_mfma_attn(
    const short* __restrict__ A, long sAo, long sAi, int lda,
    const short* __restrict__ Bm, long sBo, long sBi, int ldb,
    void* __restrict__ Cv, long sCo, long sCi, int ldc,
    int M, int N, int K, int inner) {
    __shared__ short smem[2 * 128 * 32];
    short* As = smem;
    short* Bs = smem + 128 * 32;
    int z = blockIdx.z;
    int zo = z / inner, zi = z % inner;
    const short* Ab = A + (long)zo * sAo + (long)zi * sAi;
    const short* Bb = Bm + (long)zo * sBo + (long)zi * sBi;
    long cbase = (long)zo * sCo + (long)zi * sCi;
    int row0 = blockIdx.y * 128, col0 = blockIdx.x * 128;
    int t = threadIdx.x;
    int lane = t & 63, w = t >> 6;
    int l16 = lane & 15, quad = lane >> 4;
    int wr = (w >> 1) * 64, wc = (w & 1) * 64;
    int rr = t >> 2, ch = (t & 3) * 8;
    f32x4 acc[4][4] = {};
    for (int k0 = 0; k0 < K; k0 += 32) {
        __syncthreads();
        #pragma unroll
        for (int rd = 0; rd < 2; ++rd) {
            int r = rr + rd * 64;
            int ar = row0 + r; ar = (ar < M) ? ar : (M - 1);
            gll16(Ab + (size_t)ar * lda + k0 + ch, (char*)As + rd * 4096 + t * 16);
            gll16(Bb + (size_t)(col0 + r) * ldb + k0 + ch, (char*)Bs + rd * 4096 + t * 16);
        }
        __syncthreads();
        bf16x8 af[4], bfr[4];
        #pragma unroll
        for (int i = 0; i < 4; ++i)
            af[i] = *(const bf16x8*)(As + (wr + i * 16 + l16) * 32 + quad * 8);
        #pragma unroll
        for (int j = 0; j < 4; ++j)
            bfr[j] = *(const bf16x8*)(Bs + (wc + j * 16 + l16) * 32 + quad * 8);
        #pragma unroll
        for (int i = 0; i < 4; ++i)
            #pragma unroll
            for (int j = 0; j < 4; ++j)
                acc[i][j] = __builtin_amdgcn_mfma_f32_16x16x32_bf16(af[i], bfr[j], acc[i][j], 0, 0, 0);
    }
    #pragma unroll
    for (int i = 0; i < 4; ++i) {
        #pragma unroll
        for (int r = 0; r < 4; ++r) {
            int row = row0 + wr + i * 16 + quad * 4 + r;
            if (row < M) {
                #pragma unroll
                for (int j = 0; j < 4; ++j) {
                    long idx = cbase + (size_t)row * ldc + col0 + wc + j * 16 + l16;
                    if (OBF) ((short*)Cv)[idx] = f2bf(acc[i][j][r]);
                    else     ((float*)Cv)[idx] = acc[i][j][r];
                }
            }
        }
    }
}

// ---------------------------------------------------------------------------
// QKV finish: reduce split-K partials + rotary -> bf16 Qbf (pre-scaled), Kbf, Vbf
// Cp layout: [sp][mat(q,k,v)][512][2048]
// ---------------------------------------------------------------------------
__global__ __launch_bounds__(256) void qkv_finish(
    const float* __restrict__ Cp, const float* __restrict__ fc,
    const int* __restrict__ sel_idx, const int* __restrict__ sp0,
    short* __restrict__ Qbf, short* __restrict__ Kbf, short* __restrict__ Vbf,
    int splits) {
    int r = blockIdx.x;
    int s = sel_idx[r];
    int pos = sp0[0] + s;
    const float* f = fc + (long)pos * HD_;
    const long matS = (long)ROWS_SEL * D_;
    const long spS = 3 * matS;
    const float* qp = Cp + (long)r * D_;
    const float* kp = qp + matS;
    const float* vp = qp + 2 * matS;
    const float qscale = 0.08838834764831845f;  // 1/sqrt(128)
    for (int p = threadIdx.x; p < (D_ / 2); p += 256) {
        int h = p >> 6, d2 = p & 63;
        int e0 = h * HD_ + d2 * 2;
        float q0 = 0.f, q1 = 0.f, k0 = 0.f, k1 = 0.f, v0 = 0.f, v1 = 0.f;
        for (int sp = 0; sp < splits; ++sp) {
            long off = (long)sp * spS;
            q0 += qp[off + e0]; q1 += qp[off + e0 + 1];
            k0 += kp[off + e0]; k1 += kp[off + e0 + 1];
            v0 += vp[off + e0]; v1 += vp[off + e0 + 1];
        }
        float c = f[d2 * 2], sn = f[d2 * 2 + 1];
        Qbf[(long)r * D_ + e0]     = f2bf((q0 * c - q1 * sn) * qscale);
        Qbf[(long)r * D_ + e0 + 1] = f2bf((q0 * sn + q1 * c) * qscale);
        Kbf[(long)r * D_ + e0]     = f2bf(k0 * c - k1 * sn);
        Kbf[(long)r * D_ + e0 + 1] = f2bf(k0 * sn + k1 * c);
        Vbf[(long)r * D_ + e0]     = f2bf(v0);
        Vbf[(long)r * D_ + e0 + 1] = f2bf(v1);
    }
}

// ---------------------------------------------------------------------------
// V transpose per (b,h): Vbf[b*256+key][h*128+d] -> VT[z][d][key] (bf16)
// grid: (keytiles=4, dimtiles=2, z=32)
// ---------------------------------------------------------------------------
__global__ __launch_bounds__(256) void vt_kernel(const short* __restrict__ Vbf,
                                                 short* __restrict__ VT) {
    int z = blockIdx.z;
    int b = z >> 4, h = z & 15;
    int key0 = blockIdx.x * 64, d0 = blockIdx.y * 64;
    __shared__ short L[64][72];
    int t = threadIdx.x;
    int kr = t >> 3, dc = (t & 7) * 8;
    #pragma unroll
    for (int rr = 0; rr < 2; ++rr) {
        int key = kr + rr * 32;
        union { short s[8]; int4 v; } u;
        u.v = *(const int4*)&Vbf[(size_t)(b * 256 + key0 + key) * D_ + h * 128 + d0 + dc];
        #pragma unroll
        for (int j = 0; j < 8; ++j) L[key][dc + j] = u.s[j];
    }
    __syncthreads();
    int dr = t >> 3, kc = (t & 7) * 8;
    #pragma unroll
    for (int rr = 0; rr < 2; ++rr) {
        int d = dr + rr * 32;
        union { short s[8]; int4 v; } u;
        #pragma unroll
        for (int j = 0; j < 8; ++j) u.s[j] = L[kc + j][d];
        *(int4*)&VT[((size_t)z * 128 + d0 + d) * 256 + key0 + kc] = u.v;
    }
}

// ---------------------------------------------------------------------------
// Softmax over each 256-score row -> bf16 probs
// ---------------------------------------------------------------------------
__global__ __launch_bounds__(256) void softmax_kernel(const float* __restrict__ SC,
                                                      short* __restrict__ Pbf) {
    long row = blockIdx.x;
    const float* p = SC + row * 256;
    int t = threadIdx.x;
    float v = p[t];
    __shared__ float red4[4];
    float m = block_max_256(v, red4);
    float e = expf(v - m);
    float s = block_sum_256(e, red4);
    Pbf[row * 256 + t] = f2bf(e / s);
}

// ---------------------------------------------------------------------------
// vbar: mean of selected V rows per batch -> Obf rows 512+b (bf16)
// ---------------------------------------------------------------------------
__global__ __launch_bounds__(256) void vbar_kernel(const short* __restrict__ Vbf,
                                                   short* __restrict__ Obf) {
    int b = blockIdx.y;
    int c = blockIdx.x * 256 + threadIdx.x;
    float s = 0.f;
    for (int i = 0; i < TOPK_; ++i) s += bf2f(Vbf[((long)b * TOPK_ + i) * D_ + c]);
    Obf[(long)(ROWS_SEL + b) * D_ + c] = f2bf(s * (1.f / TOPK_));
}

// ---------------------------------------------------------------------------
// Residual + RMSNorm, fused wo split-K reduce. Pp: [sp][514][2048]
// ---------------------------------------------------------------------------
__global__ __launch_bounds__(256) void resid_rmsnorm_kernel(const float* __restrict__ Pp,
                                                            int splits,
                                                            const float* __restrict__ x,
                                                            const int* __restrict__ sel_idx,
                                                            const float* __restrict__ nw,
                                                            short* __restrict__ HN) {
    int r = blockIdx.x;
    __shared__ float buf[D_];
    __shared__ float red4[4];
    const long spS = (long)ROWS_ALL * D_;
    const float* pr = Pp + (long)r * D_;
    const float* xr = nullptr;
    if (r < ROWS_SEL) {
        int b = r >> 8;
        int s = sel_idx[r];
        xr = x + ((long)b * S_ + s) * D_;
    }
    float ss = 0.f;
    for (int c = threadIdx.x; c < D_; c += 256) {
        float v = xr ? xr[c] : 0.f;
        for (int sp = 0; sp < splits; ++sp) v += pr[(long)sp * spS + c];
        buf[c] = v;
        ss += v * v;
    }
    float tot = block_sum_256(ss, red4);
    float scale = rsqrtf(tot / D_ + EPS_);
    for (int c = threadIdx.x; c < D_; c += 256)
        HN[(long)r * D_ + c] = f2bf(buf[c] * scale * nw[c]);
}

// ---------------------------------------------------------------------------
// reduce w1/w3 partials + silu-mul -> bf16. Gp: [mat][sp][514][8192], splits=2
// ---------------------------------------------------------------------------
__global__ __launch_bounds__(256) void reduce_silu_kernel(const float* __restrict__ Gp,
                                                          short* __restrict__ FF, long n) {
    long i = (long)blockIdx.x * 256 + threadIdx.x;
    if (i < n) {
        const long cz = (long)ROWS_ALL * HIDDEN_;
        float a = Gp[i] + Gp[cz + i];
        float g = Gp[2 * cz + i] + Gp[3 * cz + i];
        FF[i] = f2bf((a / (1.f + expf(-a))) * g);
    }
}

// ---------------------------------------------------------------------------
// reduce w2 partials (8) -> OUTR, float4 vectorized
// ---------------------------------------------------------------------------
__global__ __launch_bounds__(256) void w2_reduce_kernel(const float* __restrict__ Wp,
                                                        float* __restrict__ OUTR, long n4) {
    long i = (long)blockIdx.x * 256 + threadIdx.x;
    if (i < n4) {
        const long spS4 = (long)ROWS_ALL * D_ / 4;
        float4 s = ((const float4*)Wp)[i];
        for (int sp = 1; sp < 8; ++sp) {
            float4 v = ((const float4*)Wp)[(long)sp * spS4 + i];
            s.x += v.x; s.y += v.y; s.z += v.z; s.w += v.w;
        }
        ((float4*)OUTR)[i] = s;
    }
}

// ---------------------------------------------------------------------------
// Scatter rows to output (float4)
// ---------------------------------------------------------------------------
__global__ __launch_bounds__(256) void scatter_kernel(const float* __restrict__ OUTR,
                                                      const int* __restrict__ sel_pos,
                                                      float* __restrict__ out) {
    int blk = blockIdx.x;
    int b = blk >> 11;
    int p = sel_pos[blk];
    int row = (p >= 0) ? (b * TOPK_ + p) : (ROWS_SEL + b);
    const float4* src = (const float4*)(OUTR + (long)row * D_);
    float4* dst = (float4*)(out + (long)blk * D_);
    for (int c = threadIdx.x; c < D_ / 4; c += 256) dst[c] = src[c];
}

// ---------------------------------------------------------------------------
extern "C" void kernel_launch(void* const* d_in, const int* in_sizes, int n_in,
                              void* d_out, int out_size, void* d_ws, size_t ws_size,
                              hipStream_t stream) {
    const float* x        = (const float*)d_in[0];
    const int*   startpos = (const int*)d_in[1];
    const float* freqs    = (const float*)d_in[2];
    const float* router_w = (const float*)d_in[3];
    const float* wq       = (const float*)d_in[4];
    const float* wk       = (const float*)d_in[5];
    const float* wv       = (const float*)d_in[6];
    const float* wo       = (const float*)d_in[7];
    const float* w1       = (const float*)d_in[8];
    const float* w2       = (const float*)d_in[9];
    const float* w3       = (const float*)d_in[10];
    const float* attn_w   = (const float*)d_in[11];
    const float* ffn_w    = (const float*)d_in[12];

    float* out     = (float*)d_out;
    float* tw_out  = out + (long)B_ * S_ * D_;
    float* idx_out = tw_out + (long)B_ * S_;

    char* ws = (char*)d_ws;
    auto alloc = [&](size_t bytes) -> void* {
        void* p = (void*)ws;
        ws += (bytes + 255) / 256 * 256;
        return p;
    };
    int*   sel_idx = (int*)alloc((size_t)B_ * TOPK_ * sizeof(int));
    int*   sel_pos = (int*)alloc((size_t)B_ * S_ * sizeof(int));
    short* XNbf = (short*)alloc((size_t)ROWS_SEL * D_ * sizeof(short));
    short* Qbf  = (short*)alloc((size_t)ROWS_SEL * D_ * sizeof(short));
    short* Kbf  = (short*)alloc((size_t)ROWS_SEL * D_ * sizeof(short));
    short* Vbf  = (short*)alloc((size_t)ROWS_SEL * D_ * sizeof(short));
    short* VT   = (short*)alloc((size_t)B_ * H_ * HD_ * TOPK_ * sizeof(short));
    float* SC   = (float*)alloc((size_t)B_ * H_ * TOPK_ * TOPK_ * sizeof(float));
    short* Pbf  = (short*)alloc((size_t)B_ * H_ * TOPK_ * TOPK_ * sizeof(short));
    short* Obf  = (short*)alloc((size_t)ROWS_ALL * D_ * sizeof(short));
    short* HNbf = (short*)alloc((size_t)ROWS_ALL * D_ * sizeof(short));
    short* FFbf = (short*)alloc((size_t)ROWS_ALL * HIDDEN_ * sizeof(short));
    float* OUTR = (float*)alloc((size_t)ROWS_ALL * D_ * sizeof(float));
    // Split-K partial arena: max = w1/w3 partials 4 * 514 * 8192 f32 = 67.4 MB
    float* Gar  = (float*)alloc((size_t)4 * ROWS_ALL * HIDDEN_ * sizeof(float));

    // 1. Router
    router_kernel<<<B_ * S_, 256, 0, stream>>>(x, router_w, tw_out);
    // 2. Top-k
    topk_kernel<<<B_, 1024, 0, stream>>>(tw_out, idx_out, sel_idx, sel_pos);
    // 3. Gather + RMSNorm -> bf16
    gather_rmsnorm_kernel<<<ROWS_SEL, 256, 0, stream>>>(x, sel_idx, attn_w, XNbf);
    // 4. QKV GEMM (f32 weights direct), split-K=4: partials [sp][mat][512][2048]
    {
        dim3 g(D_ / 128, ROWS_SEL / 128, 3 * 4);
        gemm_mfma_w<<<g, 256, 0, stream>>>(XNbf, wq, wk, wv,
                                           Gar, (long)ROWS_SEL * D_, (long)3 * ROWS_SEL * D_,
                                           ROWS_SEL, D_, D_, D_ / 4, 4);
    }
    // 5. Reduce + rotary -> bf16 Q (pre-scaled), K, V
    qkv_finish<<<ROWS_SEL, 256, 0, stream>>>(Gar, freqs, sel_idx, startpos, Qbf, Kbf, Vbf, 4);
    // 6. V transpose per (b,h)
    {
        dim3 g(4, 2, B_ * H_);
        vt_kernel<<<g, 256, 0, stream>>>(Vbf, VT);
    }
    // 7. Scores = (Q/sqrt(HD)) K^T  (bf16 MFMA, f32 out)
    {
        dim3 g(2, 2, B_ * H_);
        gemm_mfma_attn<false><<<g, 256, 0, stream>>>(
            Qbf, (long)TOPK_ * D_, HD_, D_,
            Kbf, (long)TOPK_ * D_, HD_, D_,
            SC, (long)H_ * TOPK_ * TOPK_, (long)TOPK_ * TOPK_, TOPK_,
            TOPK_, TOPK_, HD_, H_);
    }
    // 8. Softmax -> bf16 probs
    softmax_kernel<<<B_ * H_ * TOPK_, 256, 0, stream>>>(SC, Pbf);
    // 9. O = P @ V (bf16 MFMA via VT), bf16 out into Obf (head-strided)
    {
        dim3 g(1, 2, B_ * H_);
        gemm_mfma_attn<true><<<g, 256, 0, stream>>>(
            Pbf, (long)H_ * TOPK_ * TOPK_, (long)TOPK_ * TOPK_, TOPK_,
            VT, (long)H_ * HD_ * TOPK_, (long)HD_ * TOPK_, TOPK_,
            Obf, (long)TOPK_ * D_, HD_, D_,
            TOPK_, HD_, TOPK_, H_);
    }
    // 10. vbar rows -> bf16
    {
        dim3 g(D_ / 256, B_, 1);
        vbar_kernel<<<g, 256, 0, stream>>>(Vbf, Obf);
    }
    // 11. wo projection, split-K=8: partials [sp][514][2048]
    {
        dim3 g(D_ / 128, (ROWS_ALL + 127) / 128, 8);
        gemm_mfma_w<<<g, 256, 0, stream>>>(Obf, wo, wo, wo,
                                           Gar, 0, (long)ROWS_ALL * D_,
                                           ROWS_ALL, D_, D_, D_ / 8, 8);
    }
    // 12. Residual + RMSNorm (fused wo-reduce) -> bf16
    resid_rmsnorm_kernel<<<ROWS_ALL, 256, 0, stream>>>(Gar, 8, x, sel_idx, ffn_w, HNbf);
    // 13. w1/w3 up-projections, split-K=2: partials [mat][sp][514][8192]
    {
        dim3 g(HIDDEN_ / 128, (ROWS_ALL + 127) / 128, 2 * 2);
        gemm_mfma_w<<<g, 256, 0, stream>>>(HNbf, w1, w3, w3,
                                           Gar, (long)2 * ROWS_ALL * HIDDEN_, (long)ROWS_ALL * HIDDEN_,
                                           ROWS_ALL, HIDDEN_, D_, D_ / 2, 2);
    }
    // 14. reduce + silu-mul -> bf16
    {
        long n = (long)ROWS_ALL * HIDDEN_;
        reduce_silu_kernel<<<(unsigned)((n + 255) / 256), 256, 0, stream>>>(Gar, FFbf, n);
    }
    // 15. w2 down-projection, split-K=8: partials [sp][514][2048]
    {
        dim3 g(D_ / 128, (ROWS_ALL + 127) / 128, 8);
        gemm_mfma_w<<<g, 256, 0, stream>>>(FFbf, w2, w2, w2,
                                           Gar, 0, (long)ROWS_ALL * D_,
                                           ROWS_ALL, D_, HIDDEN_, HIDDEN_ / 8, 8);
    }
    // 16. reduce w2 partials
    {
        long n4 = (long)ROWS_ALL * D_ / 4;
        w2_reduce_kernel<<<(unsigned)((n4 + 255) / 256), 256, 0, stream>>>(Gar, OUTR, n4);
    }
    // 17. Scatter
    scatter_kernel<<<B_ * S_, 256, 0, stream>>>(OUTR, sel_pos, out);
}